// Round 10
// baseline (450.874 us; speedup 1.0000x reference)
//
#include <hip/hip_runtime.h>

#define N_ATOMS 100000
#define M_NBRS 12
#define ATOM_F 64
#define NBR_F 41
#define OUT_DIM 128   // 2*ATOM_F
#define IN_DIM 169    // 2*ATOM_F + NBR_F
#define N_GROUPS (N_ATOMS / 16)   // 6250, exact
#define LOG2E 1.44269504f
#define LN2   0.69314718f

typedef __attribute__((ext_vector_type(8))) short short8;
typedef __attribute__((ext_vector_type(4))) float f32x4;
typedef __attribute__((ext_vector_type(4))) unsigned u32x4;

// packed f32x2 -> bf16x2 (RNE): lo16 = bf16(a), hi16 = bf16(b). 1 VALU inst.
__device__ __forceinline__ unsigned cvt_pk(float a, float b) {
    unsigned r;
    asm("v_cvt_pk_bf16_f32 %0, %1, %2" : "=v"(r) : "v"(a), "v"(b));
    return r;
}
// hardware transcendentals via BUILTINS (not inline asm): trans ops have a
// required wait-state before the consumer; the backend inserts it for
// intrinsics but cannot see inside inline asm (round-8 NaN root cause).
__device__ __forceinline__ float fexp2(float x) { return __builtin_amdgcn_exp2f(x); }
__device__ __forceinline__ float flog2(float x) { return __builtin_amdgcn_logf(x); }
__device__ __forceinline__ float frcp(float x)  { return __builtin_amdgcn_rcpf(x); }
__device__ __forceinline__ float softplus_f(float x) {   // k_final only
    return fmaxf(x, 0.f) + __logf(1.f + __expf(-fabsf(x)));
}

// ---------------------------------------------------------------------------
// P: per-atom precompute + EDGE REPACK.
//   abf[a]  : bf16 atom features, fragment layout (UNSCALED — A operand).
//   A1P     : y = LOG2E*(Wself·a + b), bf16 (filter,core) pairs, consumer
//             lane layout (same lane produces and consumes).
//   EP      : nbr_fea transposed to m-major slabs, bf16, 48 elems (96 B,
//             16B-aligned, zero-padded) per (m, atom) row.
// WHY EP: rounds 0-9 all show k_msg dur = FETCH / achieved-BW with
// achieved-BW pinned at 1.0-2.5 TB/s — the edge stream is 164B chunks at
// 1968B stride (m-interleaved), a DRAM/MLP-hostile pattern.  m-major bf16
// slabs make k_msg's edge reads fully coalesced (wave streams contiguous
// 1.5KB per m-iter) and 43% smaller.  Producer is input-linear
// (T = a*12+m -> reads nbr+T*41 contiguous; writes 12 sequential streams).
// ---------------------------------------------------------------------------
__global__ __launch_bounds__(256, 4) void k_prep(
    const float* __restrict__ atom, const float* __restrict__ nbr,
    const float* __restrict__ W, const float* __restrict__ bias,
    unsigned* __restrict__ abf_u32, unsigned* __restrict__ A1P,
    unsigned* __restrict__ EP, float* __restrict__ SUM)
{
    __shared__ __align__(16) unsigned BFp[16 * 64 * 4];   // 16 KB
    const int tid = threadIdx.x;
    const int w = tid >> 6, l = tid & 63;
    const int r = l & 15, g = l >> 4;

    if (blockIdx.x == 0 && tid < 128) SUM[tid] = 0.f;

    // stage W_self fragments (×LOG2E): 16 frags x 64 lanes, 4 per thread
    #pragma unroll
    for (int s = 0; s < 4; ++s) {
        int f = s * 4 + w;              // frag = nt*2 + kk
        int nt = f >> 1, kk = f & 1;
        int col = nt * 16 + r;
        int kbase = kk * 32 + g * 8;
        const float* wp = W + col * IN_DIM + kbase;   // k < 64 always valid
        u32x4 pk;
        pk[0] = cvt_pk(wp[0] * LOG2E, wp[1] * LOG2E);
        pk[1] = cvt_pk(wp[2] * LOG2E, wp[3] * LOG2E);
        pk[2] = cvt_pk(wp[4] * LOG2E, wp[5] * LOG2E);
        pk[3] = cvt_pk(wp[6] * LOG2E, wp[7] * LOG2E);
        *reinterpret_cast<u32x4*>(&BFp[(f * 64 + l) * 4]) = pk;
    }
    __syncthreads();

    // ---- edge repack (ALL threads; before any early exit) ----
    {
        const int tot = N_ATOMS * M_NBRS;          // 1.2M rows
        const int stride = gridDim.x * 256;
        for (int T = blockIdx.x * 256 + tid; T < tot; T += stride) {
            int m = T - (T / M_NBRS) * M_NBRS;     // T % 12
            int a = T / M_NBRS;
            const float* ip = nbr + (size_t)T * NBR_F;   // (a*12+m)*41
            unsigned o[24];
            #pragma unroll
            for (int u = 0; u < 20; ++u) o[u] = cvt_pk(ip[2 * u], ip[2 * u + 1]);
            o[20] = cvt_pk(ip[40], 0.f);
            o[21] = 0u; o[22] = 0u; o[23] = 0u;
            unsigned* op = EP + ((size_t)m * N_ATOMS + a) * 24;
            #pragma unroll
            for (int q = 0; q < 6; ++q)
                *reinterpret_cast<u32x4*>(op + q * 4) =
                    *reinterpret_cast<const u32x4*>(&o[q * 4]);
        }
    }

    const int gw = blockIdx.x * 4 + w;
    if (gw >= N_GROUPS) return;
    const int base = gw * 16;

    float bb[8];
    #pragma unroll
    for (int nt = 0; nt < 8; ++nt) bb[nt] = bias[nt * 16 + r] * LOG2E;

    // A fragments: 8 contiguous, 16B-aligned floats per (lane, kk) — UNSCALED
    union { u32x4 u; short8 s; } af[2];
    #pragma unroll
    for (int kk = 0; kk < 2; ++kk) {
        const float4* ap = reinterpret_cast<const float4*>(atom)
                           + (size_t)(base + r) * 16 + kk * 8 + g * 2;
        float4 v0 = ap[0], v1 = ap[1];
        af[kk].u[0] = cvt_pk(v0.x, v0.y); af[kk].u[1] = cvt_pk(v0.z, v0.w);
        af[kk].u[2] = cvt_pk(v1.x, v1.y); af[kk].u[3] = cvt_pk(v1.z, v1.w);
        *reinterpret_cast<u32x4*>(&abf_u32[(size_t)(base + r) * 32 + kk * 16 + g * 4])
            = af[kk].u;
    }

    // MFMA: filter (nt) and core (nt+4), pack into A1P lane layout
    u32x4 outp[4];   // [r4][nt]
    #pragma unroll
    for (int nt = 0; nt < 4; ++nt) {
        f32x4 accf = {0.f,0.f,0.f,0.f}, accc = {0.f,0.f,0.f,0.f};
        #pragma unroll
        for (int kk = 0; kk < 2; ++kk) {
            union { u32x4 u; short8 s; } uf, uc;
            uf.u = *reinterpret_cast<const u32x4*>(&BFp[((nt * 2 + kk) * 64 + l) * 4]);
            uc.u = *reinterpret_cast<const u32x4*>(&BFp[(((nt + 4) * 2 + kk) * 64 + l) * 4]);
            accf = __builtin_amdgcn_mfma_f32_16x16x32_bf16(af[kk].s, uf.s, accf, 0,0,0);
            accc = __builtin_amdgcn_mfma_f32_16x16x32_bf16(af[kk].s, uc.s, accc, 0,0,0);
        }
        #pragma unroll
        for (int r4 = 0; r4 < 4; ++r4)
            outp[r4][nt] = cvt_pk(accf[r4] + bb[nt], accc[r4] + bb[nt + 4]);
    }
    #pragma unroll
    for (int r4 = 0; r4 < 4; ++r4)
        *reinterpret_cast<u32x4*>(&A1P[(size_t)gw * 1024 + r4 * 256 + l * 4]) = outp[r4];
}

// ---------------------------------------------------------------------------
// M: one 16-atom group per wave, 12 MFMA tiles (one per neighbor slot).
// A-fragments straight from global; B fragments frag-linear in LDS (32 KB,
// conflict-free); opaque-asm blocks LICM of the B ds_reads.
// ROUND-10: edges come from EP (m-major bf16 slabs): per m-iter each lane
// does TWO aligned dwordx4 loads — the wave streams a contiguous 1.5 KB
// block (coalesced), replacing ~12 scalar strided loads + 8 cvt_pk +
// divergent masking.  kk=3 needs no mask: g>=2 lanes pair with B-rows
// 112..127 which are staged zero; g==1 reads bytes 80..95 = {bf16(f40),0..}
// (producer zero-pads).  Gathers stay 1-deep; activation in y-space
// (LOG2E folded at staging): sigmoid = rcp(1+2^-y), softplus = ln2*log2(1+2^y).
// BN partial stats fused (128 atomics per block).
// ---------------------------------------------------------------------------
__global__ __launch_bounds__(256, 4) void k_msg(
    const float* __restrict__ atom, const float* __restrict__ W,
    const int* __restrict__ idx, const unsigned* __restrict__ abf,
    const unsigned* __restrict__ A1P, const unsigned* __restrict__ EP,
    float* __restrict__ X, float* __restrict__ SUM)
{
    __shared__ __align__(16) unsigned BF[32 * 64 * 4];   // 32 KB, frag-linear
    const int tid = threadIdx.x;
    const int w = tid >> 6, l = tid & 63;
    const int c = l & 15, g = l >> 4;

    // stage W_msg fragments (×LOG2E): 32 frags x 64 lanes, 8 per thread
    #pragma unroll
    for (int s = 0; s < 8; ++s) {
        int f = s * 4 + w;
        int nt = f >> 2, kk = f & 3;
        int col = nt * 16 + c;
        int kbase = kk * 32 + g * 8;
        const float* wp = W + col * IN_DIM + 64 + kbase;
        u32x4 pk;
        float v[8];
        #pragma unroll
        for (int j = 0; j < 8; ++j)
            v[j] = (kbase + j < 105) ? wp[j] * LOG2E : 0.f;   // K-pad 105..127
        pk[0] = cvt_pk(v[0], v[1]); pk[1] = cvt_pk(v[2], v[3]);
        pk[2] = cvt_pk(v[4], v[5]); pk[3] = cvt_pk(v[6], v[7]);
        *reinterpret_cast<u32x4*>(&BF[(f * 64 + l) * 4]) = pk;
    }
    __syncthreads();

    const int gw = blockIdx.x * 4 + w;
    float sum_p[4] = {0.f,0.f,0.f,0.f}, sq_p[4] = {0.f,0.f,0.f,0.f};

    if (gw < N_GROUPS) {
        const int base = gw * 16;
        // A1 packed pairs (coalesced b128); stays packed — 16 regs
        u32x4 a1q[4];
        #pragma unroll
        for (int r4 = 0; r4 < 4; ++r4)
            a1q[r4] = *reinterpret_cast<const u32x4*>(
                &A1P[(size_t)gw * 1024 + r4 * 256 + l * 4]);

        float gs[4][4];
        #pragma unroll
        for (int r4 = 0; r4 < 4; ++r4)
          #pragma unroll
          for (int p = 0; p < 4; ++p) gs[r4][p] = 0.f;

        const int irow = (base + c) * M_NBRS;              // this lane's row
        // per-lane EP byte offsets (within a slab); slab stride = N*96 B
        const char* EPb = reinterpret_cast<const char*>(EP);
        const size_t e2off = (size_t)(base + c) * 96 + (size_t)g * 16;
        const size_t e3off = (size_t)(base + c) * 96 + 64 + (g == 1 ? 16 : 0);
        const size_t slab = (size_t)N_ATOMS * 96;

        unsigned bofs = (unsigned)l * 16u;   // per-lane BF byte offset (opaque)

        // ---- 1-deep pipeline warm-up ----
        u32x4 at0, at1, at0n, at1n, e2, e3, e2n, e3n;
        int jn;
        {
            int j0 = idx[irow];
            at0 = *reinterpret_cast<const u32x4*>(abf + (size_t)j0 * 32 + g * 4);
            at1 = *reinterpret_cast<const u32x4*>(abf + (size_t)j0 * 32 + 16 + g * 4);
            e2 = *reinterpret_cast<const u32x4*>(EPb + e2off);
            e3 = *reinterpret_cast<const u32x4*>(EPb + e3off);
        }
        jn = idx[irow + 1];

        #pragma unroll 1
        for (int m = 0; m < M_NBRS; ++m) {
            // ---- prefetch tile m+1 data, tile m+2 index ----
            if (m + 1 < M_NBRS) {
                at0n = *reinterpret_cast<const u32x4*>(abf + (size_t)jn * 32 + g * 4);
                at1n = *reinterpret_cast<const u32x4*>(abf + (size_t)jn * 32 + 16 + g * 4);
                e2n = *reinterpret_cast<const u32x4*>(EPb + (m + 1) * slab + e2off);
                e3n = *reinterpret_cast<const u32x4*>(EPb + (m + 1) * slab + e3off);
                if (m + 2 < M_NBRS) jn = idx[irow + m + 2];
            }
            // ---- compute tile m ----
            asm volatile("" : "+v"(bofs));   // block LICM of B-fragment reads
            const char* bsb = reinterpret_cast<const char*>(BF);
            union { u32x4 u; short8 s; } a0, a1, a2, a3;
            a0.u = at0; a1.u = at1; a2.u = e2; a3.u = e3;
            #pragma unroll
            for (int p = 0; p < 4; ++p) {
                // self-term (already ×LOG2E) rides in as the accumulator init
                f32x4 accf, accc;
                #pragma unroll
                for (int r4 = 0; r4 < 4; ++r4) {
                    unsigned v = a1q[r4][p];
                    accf[r4] = __uint_as_float(v << 16);
                    accc[r4] = __uint_as_float(v & 0xffff0000u);
                }
                #pragma unroll
                for (int kk = 0; kk < 4; ++kk) {
                    union { u32x4 u; short8 s; } uf, uc;
                    uf.u = *reinterpret_cast<const u32x4*>(
                        bsb + bofs + (unsigned)((p * 4 + kk) * 64 * 16));
                    uc.u = *reinterpret_cast<const u32x4*>(
                        bsb + bofs + (unsigned)(((p + 4) * 4 + kk) * 64 * 16));
                    short8 afk = (kk == 0) ? a0.s : (kk == 1) ? a1.s
                               : (kk == 2) ? a2.s : a3.s;
                    accf = __builtin_amdgcn_mfma_f32_16x16x32_bf16(afk, uf.s, accf, 0,0,0);
                    accc = __builtin_amdgcn_mfma_f32_16x16x32_bf16(afk, uc.s, accc, 0,0,0);
                }
                // gate in y-space: sigmoid = rcp(1+2^-y), softplus = ln2*log2(1+2^y)
                #pragma unroll
                for (int r4 = 0; r4 < 4; ++r4) {
                    float sig = frcp(1.f + fexp2(-accf[r4]));
                    float sp  = flog2(1.f + fexp2(accc[r4])) * LN2;
                    gs[r4][p] += sig * sp;
                }
            }
            // ---- rotate ----
            at0 = at0n; at1 = at1n; e2 = e2n; e3 = e3n;
        }
        // ---- epilogue: x = atom + msg, store, accumulate BN partials ----
        #pragma unroll
        for (int r4 = 0; r4 < 4; ++r4) {
            int o = (base + g * 4 + r4) * ATOM_F + c;
            #pragma unroll
            for (int p = 0; p < 4; ++p) {
                float x = atom[o + p * 16] + gs[r4][p];
                X[o + p * 16] = x;
                sum_p[p] += x;
                sq_p[p] += x * x;
            }
        }
    }

    // ---- BN stats: wave reduce over g, block reduce over waves, 1 atomic ----
    #pragma unroll
    for (int p = 0; p < 4; ++p) {
        sum_p[p] += __shfl_xor(sum_p[p], 16, 64);
        sum_p[p] += __shfl_xor(sum_p[p], 32, 64);
        sq_p[p]  += __shfl_xor(sq_p[p], 16, 64);
        sq_p[p]  += __shfl_xor(sq_p[p], 32, 64);
    }
    __syncthreads();   // all waves done reading BF before reuse as scratch
    float* Rs = reinterpret_cast<float*>(BF);
    if (g == 0) {
        #pragma unroll
        for (int p = 0; p < 4; ++p) {
            Rs[w * 128 + p * 16 + c] = sum_p[p];
            Rs[512 + w * 128 + p * 16 + c] = sq_p[p];
        }
    }
    __syncthreads();
    if (tid < 128) {
        int q = tid & 63;
        int o = (tid >> 6) * 512;
        float v = Rs[o + q] + Rs[o + 128 + q] + Rs[o + 256 + q] + Rs[o + 384 + q];
        atomicAdd(&SUM[tid], v);
    }
}

// ---------------------------------------------------------------------------
// Final: derive BN scale/shift inline from SUM (L2-broadcast reads), then
// normalize + softplus in place.
// ---------------------------------------------------------------------------
__global__ void k_final(float* __restrict__ X, const float* __restrict__ SUM,
                        const float* __restrict__ gamma, const float* __restrict__ beta)
{
    int q = blockIdx.x * 256 + threadIdx.x;   // exactly N*64/4 threads
    int fb = (q & 15);                         // float4 index within feature row
    const float4* S4 = reinterpret_cast<const float4*>(SUM);
    float4 s1 = S4[fb];            // sums for features fb*4..fb*4+3
    float4 s2 = S4[16 + fb];       // sq-sums
    float4 gm = reinterpret_cast<const float4*>(gamma)[fb];
    float4 bt = reinterpret_cast<const float4*>(beta)[fb];
    const float inv_n = 1.f / N_ATOMS;
    float4 x = reinterpret_cast<const float4*>(X)[q];
    float4 o;
    {
        float mean = s1.x * inv_n, msq = s2.x * inv_n;
        float sc = rsqrtf(msq - mean * mean + 1e-5f) * gm.x;
        o.x = softplus_f(x.x * sc + (bt.x - mean * sc));
    }
    {
        float mean = s1.y * inv_n, msq = s2.y * inv_n;
        float sc = rsqrtf(msq - mean * mean + 1e-5f) * gm.y;
        o.y = softplus_f(x.y * sc + (bt.y - mean * sc));
    }
    {
        float mean = s1.z * inv_n, msq = s2.z * inv_n;
        float sc = rsqrtf(msq - mean * mean + 1e-5f) * gm.z;
        o.z = softplus_f(x.z * sc + (bt.z - mean * sc));
    }
    {
        float mean = s1.w * inv_n, msq = s2.w * inv_n;
        float sc = rsqrtf(msq - mean * mean + 1e-5f) * gm.w;
        o.w = softplus_f(x.w * sc + (bt.w - mean * sc));
    }
    reinterpret_cast<float4*>(X)[q] = o;
}

extern "C" void kernel_launch(void* const* d_in, const int* in_sizes, int n_in,
                              void* d_out, int out_size, void* d_ws, size_t ws_size,
                              hipStream_t stream)
{
    const float* atom  = (const float*)d_in[0];
    const float* nbr   = (const float*)d_in[1];
    const float* W     = (const float*)d_in[2];
    const float* bias  = (const float*)d_in[3];
    const float* gamma = (const float*)d_in[4];
    const float* beta  = (const float*)d_in[5];
    const int*   idx   = (const int*)d_in[6];
    float* X = (float*)d_out;   // x pre-BN lives in d_out, finalized in place

    char* ws = (char*)d_ws;
    unsigned* abf = (unsigned*)ws;                                     // N*32 u32   (12.8 MB)
    unsigned* A1P = (unsigned*)(ws + (size_t)N_ATOMS * 32 * 4);        // 6250*1024 u32 (25.6 MB)
    unsigned* EP  = (unsigned*)(ws + (size_t)N_ATOMS * 32 * 4
                                   + (size_t)N_GROUPS * 1024 * 4);     // 1.2M*24 u32 (115.2 MB)
    float* SUM    = (float*)(ws + (size_t)N_ATOMS * 32 * 4
                                + (size_t)N_GROUPS * 1024 * 4
                                + (size_t)N_ATOMS * M_NBRS * 24 * 4);  // 128 f32

    const int blocks = (N_GROUPS + 3) / 4;   // 1563: one group per wave
    hipLaunchKernelGGL(k_prep,  dim3(blocks), dim3(256), 0, stream,
                       atom, nbr, W, bias, abf, A1P, EP, SUM);
    hipLaunchKernelGGL(k_msg,   dim3(blocks), dim3(256), 0, stream,
                       atom, W, idx, abf, A1P, EP, X, SUM);
    hipLaunchKernelGGL(k_final, dim3(6250),   dim3(256), 0, stream, X, SUM, gamma, beta);
}

// Round 11
// 437.261 us; speedup vs baseline: 1.0311x; 1.0311x over previous
//
#include <hip/hip_runtime.h>

#define N_ATOMS 100000
#define M_NBRS 12
#define ATOM_F 64
#define NBR_F 41
#define OUT_DIM 128   // 2*ATOM_F
#define IN_DIM 169    // 2*ATOM_F + NBR_F
#define N_GROUPS (N_ATOMS / 16)   // 6250, exact
#define LOG2E 1.44269504f
#define LN2   0.69314718f

typedef __attribute__((ext_vector_type(8))) short short8;
typedef __attribute__((ext_vector_type(4))) float f32x4;
typedef __attribute__((ext_vector_type(4))) unsigned u32x4;

// packed f32x2 -> bf16x2 (RNE): lo16 = bf16(a), hi16 = bf16(b). 1 VALU inst.
__device__ __forceinline__ unsigned cvt_pk(float a, float b) {
    unsigned r;
    asm("v_cvt_pk_bf16_f32 %0, %1, %2" : "=v"(r) : "v"(a), "v"(b));
    return r;
}
// hardware transcendentals via BUILTINS (not inline asm): trans ops have a
// required wait-state before the consumer; the backend inserts it for
// intrinsics but cannot see inside inline asm (round-8 NaN root cause).
__device__ __forceinline__ float fexp2(float x) { return __builtin_amdgcn_exp2f(x); }
__device__ __forceinline__ float flog2(float x) { return __builtin_amdgcn_logf(x); }
__device__ __forceinline__ float frcp(float x)  { return __builtin_amdgcn_rcpf(x); }
__device__ __forceinline__ float softplus_f(float x) {   // k_final only
    return fmaxf(x, 0.f) + __logf(1.f + __expf(-fabsf(x)));
}

// ---------------------------------------------------------------------------
// P: minimal — bf16-convert atom features into MFMA fragment layout.
//   abf[a*32 + kk*16 + g*4 + t] = bf16 pair (features kk*32+g*8+2t, +1)
// (Round-11: A1P round-trip (51 MB) eliminated — k_msg computes the self
// term in-place, since producer lane == consumer lane.  EP repack (round
// 10) reverted: its 230 MB extra traffic at the ~2.2 TB/s achieved-BW cap
// cost more than the k_msg coalescing gain repaid.)
// ---------------------------------------------------------------------------
__global__ __launch_bounds__(256, 4) void k_prep(
    const float* __restrict__ atom, unsigned* __restrict__ abf_u32,
    float* __restrict__ SUM)
{
    const int tid = threadIdx.x;
    const int w = tid >> 6, l = tid & 63;
    const int r = l & 15, g = l >> 4;

    if (blockIdx.x == 0 && tid < 128) SUM[tid] = 0.f;

    const int gw = blockIdx.x * 4 + w;
    if (gw >= N_GROUPS) return;
    const int base = gw * 16;

    #pragma unroll
    for (int kk = 0; kk < 2; ++kk) {
        const float4* ap = reinterpret_cast<const float4*>(atom)
                           + (size_t)(base + r) * 16 + kk * 8 + g * 2;
        float4 v0 = ap[0], v1 = ap[1];
        u32x4 u;
        u[0] = cvt_pk(v0.x, v0.y); u[1] = cvt_pk(v0.z, v0.w);
        u[2] = cvt_pk(v1.x, v1.y); u[3] = cvt_pk(v1.z, v1.w);
        *reinterpret_cast<u32x4*>(&abf_u32[(size_t)(base + r) * 32 + kk * 16 + g * 4]) = u;
    }
}

// ---------------------------------------------------------------------------
// M: one 16-atom group per wave, 12 MFMA tiles (one per neighbor slot).
// Phase 0: W_self frags -> BF[0:16KB], barrier, each wave computes its own
//   a1q = bf16-packed LOG2E*(Wself·a+b) via 8 MFMAs (producer lane ==
//   consumer lane: identical layout to the old A1P, zero shuffles).
// Phase 1: W_msg frags overwrite BF (32 KB, frag-linear, conflict-free);
//   opaque-asm blocks LICM of the per-tile B ds_reads.
// m-loop: A-frags straight from global.  Edges = the HBM-latency stream ->
//   2-DEEP prefetch (tile compute ~500 cyc vs ~900 cyc HBM; 1-deep left
//   ~400 cyc exposed).  Gathers stay 1-deep (L2/L3 class; r7 showed
//   deepening them is null).  Activation in y-space (LOG2E folded):
//   sigmoid = rcp(1+2^-y), softplus = ln2*log2(1+2^y).
// BN partial stats fused (128 atomics per block).
// ---------------------------------------------------------------------------
struct EBuf { unsigned p2[4]; unsigned p3[4]; };   // packed bf16 edge frags

__device__ __forceinline__ EBuf load_edges(const float* __restrict__ ep, int g)
{
    EBuf b;
    f32x4 v0, v1;   // 16B loads at 4B alignment (dword-aligned, legal)
    __builtin_memcpy(&v0, ep + g * 8, 16);
    __builtin_memcpy(&v1, ep + g * 8 + 4, 16);
    b.p2[0] = cvt_pk(v0[0], v0[1]); b.p2[1] = cvt_pk(v0[2], v0[3]);
    b.p2[2] = cvt_pk(v1[0], v1[1]); b.p2[3] = cvt_pk(v1[2], v1[3]);
    b.p3[0] = b.p3[1] = b.p3[2] = b.p3[3] = 0u;
    if (g == 0) {
        f32x4 u0, u1;
        __builtin_memcpy(&u0, ep + 32, 16);
        __builtin_memcpy(&u1, ep + 36, 16);
        b.p3[0] = cvt_pk(u0[0], u0[1]); b.p3[1] = cvt_pk(u0[2], u0[3]);
        b.p3[2] = cvt_pk(u1[0], u1[1]); b.p3[3] = cvt_pk(u1[2], u1[3]);
    } else if (g == 1) {
        b.p3[0] = cvt_pk(ep[40], 0.f);                 // float 40, pad 41
    }
    return b;
}

__global__ __launch_bounds__(256, 4) void k_msg(
    const float* __restrict__ atom, const float* __restrict__ nbr,
    const float* __restrict__ W, const float* __restrict__ bias,
    const int* __restrict__ idx, const unsigned* __restrict__ abf,
    float* __restrict__ X, float* __restrict__ SUM)
{
    __shared__ __align__(16) unsigned BF[32 * 64 * 4];   // 32 KB, frag-linear
    const int tid = threadIdx.x;
    const int w = tid >> 6, l = tid & 63;
    const int c = l & 15, g = l >> 4;

    const int gw = blockIdx.x * 4 + w;
    const bool active = (gw < N_GROUPS);
    const int base = gw * 16;

    // ---- phase 0: W_self fragments (×LOG2E) into BF[0 : 16 frags) ----
    #pragma unroll
    for (int s = 0; s < 4; ++s) {
        int f = s * 4 + w;              // frag = nt*2 + kk, 16 total
        int nt = f >> 1, kk = f & 1;
        int col = nt * 16 + c;
        int kbase = kk * 32 + g * 8;
        const float* wp = W + col * IN_DIM + kbase;   // k < 64 always valid
        u32x4 pk;
        pk[0] = cvt_pk(wp[0] * LOG2E, wp[1] * LOG2E);
        pk[1] = cvt_pk(wp[2] * LOG2E, wp[3] * LOG2E);
        pk[2] = cvt_pk(wp[4] * LOG2E, wp[5] * LOG2E);
        pk[3] = cvt_pk(wp[6] * LOG2E, wp[7] * LOG2E);
        *reinterpret_cast<u32x4*>(&BF[(f * 64 + l) * 4]) = pk;
    }
    __syncthreads();

    // ---- self term: a1q = bf16-pair(LOG2E*(Wself·a + b)) in consumer layout ----
    u32x4 a1q[4];
    #pragma unroll
    for (int r4 = 0; r4 < 4; ++r4) a1q[r4] = u32x4{0u, 0u, 0u, 0u};
    if (active) {
        float bb[8];
        #pragma unroll
        for (int nt = 0; nt < 8; ++nt) bb[nt] = bias[nt * 16 + c] * LOG2E;
        union { u32x4 u; short8 s; } af[2];
        #pragma unroll
        for (int kk = 0; kk < 2; ++kk)
            af[kk].u = *reinterpret_cast<const u32x4*>(
                &abf[(size_t)(base + c) * 32 + kk * 16 + g * 4]);
        #pragma unroll
        for (int nt = 0; nt < 4; ++nt) {
            f32x4 accf = {0.f,0.f,0.f,0.f}, accc = {0.f,0.f,0.f,0.f};
            #pragma unroll
            for (int kk = 0; kk < 2; ++kk) {
                union { u32x4 u; short8 s; } uf, uc;
                uf.u = *reinterpret_cast<const u32x4*>(&BF[((nt * 2 + kk) * 64 + l) * 4]);
                uc.u = *reinterpret_cast<const u32x4*>(&BF[(((nt + 4) * 2 + kk) * 64 + l) * 4]);
                accf = __builtin_amdgcn_mfma_f32_16x16x32_bf16(af[kk].s, uf.s, accf, 0,0,0);
                accc = __builtin_amdgcn_mfma_f32_16x16x32_bf16(af[kk].s, uc.s, accc, 0,0,0);
            }
            #pragma unroll
            for (int r4 = 0; r4 < 4; ++r4)
                a1q[r4][nt] = cvt_pk(accf[r4] + bb[nt], accc[r4] + bb[nt + 4]);
        }
    }
    __syncthreads();   // all waves done reading W_self before overwrite

    // ---- phase 1: W_msg fragments (×LOG2E) overwrite BF (32 frags) ----
    #pragma unroll
    for (int s = 0; s < 8; ++s) {
        int f = s * 4 + w;
        int nt = f >> 2, kk = f & 3;
        int col = nt * 16 + c;
        int kbase = kk * 32 + g * 8;
        const float* wp = W + col * IN_DIM + 64 + kbase;
        u32x4 pk;
        float v[8];
        #pragma unroll
        for (int j = 0; j < 8; ++j)
            v[j] = (kbase + j < 105) ? wp[j] * LOG2E : 0.f;   // K-pad 105..127
        pk[0] = cvt_pk(v[0], v[1]); pk[1] = cvt_pk(v[2], v[3]);
        pk[2] = cvt_pk(v[4], v[5]); pk[3] = cvt_pk(v[6], v[7]);
        *reinterpret_cast<u32x4*>(&BF[(f * 64 + l) * 4]) = pk;
    }
    __syncthreads();

    float sum_p[4] = {0.f,0.f,0.f,0.f}, sq_p[4] = {0.f,0.f,0.f,0.f};

    if (active) {
        float gs[4][4];
        #pragma unroll
        for (int r4 = 0; r4 < 4; ++r4)
          #pragma unroll
          for (int p = 0; p < 4; ++p) gs[r4][p] = 0.f;

        const int irow = (base + c) * M_NBRS;              // this lane's row
        const float* erow = nbr + (size_t)irow * NBR_F;

        unsigned bofs = (unsigned)l * 16u;   // per-lane BF byte offset (opaque)

        // ---- warm-up: gathers 1-deep, edges 2-deep ----
        u32x4 at0, at1, at0n, at1n;
        EBuf eb, ebn, eb2;
        int jn;
        {
            int j0 = idx[irow];
            at0 = *reinterpret_cast<const u32x4*>(abf + (size_t)j0 * 32 + g * 4);
            at1 = *reinterpret_cast<const u32x4*>(abf + (size_t)j0 * 32 + 16 + g * 4);
            eb  = load_edges(erow, g);
            ebn = load_edges(erow + NBR_F, g);
        }
        jn = idx[irow + 1];

        #pragma unroll 1
        for (int m = 0; m < M_NBRS; ++m) {
            // ---- prefetch: gather m+1, idx m+2, edges m+2 ----
            if (m + 1 < M_NBRS) {
                at0n = *reinterpret_cast<const u32x4*>(abf + (size_t)jn * 32 + g * 4);
                at1n = *reinterpret_cast<const u32x4*>(abf + (size_t)jn * 32 + 16 + g * 4);
                if (m + 2 < M_NBRS) jn = idx[irow + m + 2];
            }
            if (m + 2 < M_NBRS)
                eb2 = load_edges(erow + (m + 2) * NBR_F, g);
            // ---- compute tile m ----
            asm volatile("" : "+v"(bofs));   // block LICM of B-fragment reads
            const char* bsb = reinterpret_cast<const char*>(BF);
            union { u32x4 u; short8 s; } a0, a1, a2, a3;
            a0.u = at0; a1.u = at1;
            a2.u[0] = eb.p2[0]; a2.u[1] = eb.p2[1]; a2.u[2] = eb.p2[2]; a2.u[3] = eb.p2[3];
            a3.u[0] = eb.p3[0]; a3.u[1] = eb.p3[1]; a3.u[2] = eb.p3[2]; a3.u[3] = eb.p3[3];
            #pragma unroll
            for (int p = 0; p < 4; ++p) {
                // self-term (already ×LOG2E) rides in as the accumulator init
                f32x4 accf, accc;
                #pragma unroll
                for (int r4 = 0; r4 < 4; ++r4) {
                    unsigned v = a1q[r4][p];
                    accf[r4] = __uint_as_float(v << 16);
                    accc[r4] = __uint_as_float(v & 0xffff0000u);
                }
                #pragma unroll
                for (int kk = 0; kk < 4; ++kk) {
                    union { u32x4 u; short8 s; } uf, uc;
                    uf.u = *reinterpret_cast<const u32x4*>(
                        bsb + bofs + (unsigned)((p * 4 + kk) * 64 * 16));
                    uc.u = *reinterpret_cast<const u32x4*>(
                        bsb + bofs + (unsigned)(((p + 4) * 4 + kk) * 64 * 16));
                    short8 afk = (kk == 0) ? a0.s : (kk == 1) ? a1.s
                               : (kk == 2) ? a2.s : a3.s;
                    accf = __builtin_amdgcn_mfma_f32_16x16x32_bf16(afk, uf.s, accf, 0,0,0);
                    accc = __builtin_amdgcn_mfma_f32_16x16x32_bf16(afk, uc.s, accc, 0,0,0);
                }
                // gate in y-space: sigmoid = rcp(1+2^-y), softplus = ln2*log2(1+2^y)
                #pragma unroll
                for (int r4 = 0; r4 < 4; ++r4) {
                    float sig = frcp(1.f + fexp2(-accf[r4]));
                    float sp  = flog2(1.f + fexp2(accc[r4])) * LN2;
                    gs[r4][p] += sig * sp;
                }
            }
            // ---- rotate (static names, rule-#20 safe) ----
            at0 = at0n; at1 = at1n; eb = ebn; ebn = eb2;
        }
        // ---- epilogue: x = atom + msg, store, accumulate BN partials ----
        #pragma unroll
        for (int r4 = 0; r4 < 4; ++r4) {
            int o = (base + g * 4 + r4) * ATOM_F + c;
            #pragma unroll
            for (int p = 0; p < 4; ++p) {
                float x = atom[o + p * 16] + gs[r4][p];
                X[o + p * 16] = x;
                sum_p[p] += x;
                sq_p[p] += x * x;
            }
        }
    }

    // ---- BN stats: wave reduce over g, block reduce over waves, 1 atomic ----
    #pragma unroll
    for (int p = 0; p < 4; ++p) {
        sum_p[p] += __shfl_xor(sum_p[p], 16, 64);
        sum_p[p] += __shfl_xor(sum_p[p], 32, 64);
        sq_p[p]  += __shfl_xor(sq_p[p], 16, 64);
        sq_p[p]  += __shfl_xor(sq_p[p], 32, 64);
    }
    __syncthreads();   // all waves done reading BF before reuse as scratch
    float* Rs = reinterpret_cast<float*>(BF);
    if (g == 0) {
        #pragma unroll
        for (int p = 0; p < 4; ++p) {
            Rs[w * 128 + p * 16 + c] = sum_p[p];
            Rs[512 + w * 128 + p * 16 + c] = sq_p[p];
        }
    }
    __syncthreads();
    if (tid < 128) {
        int q = tid & 63;
        int o = (tid >> 6) * 512;
        float v = Rs[o + q] + Rs[o + 128 + q] + Rs[o + 256 + q] + Rs[o + 384 + q];
        atomicAdd(&SUM[tid], v);
    }
}

// ---------------------------------------------------------------------------
// Final: derive BN scale/shift inline from SUM (L2-broadcast reads), then
// normalize + softplus in place.
// ---------------------------------------------------------------------------
__global__ void k_final(float* __restrict__ X, const float* __restrict__ SUM,
                        const float* __restrict__ gamma, const float* __restrict__ beta)
{
    int q = blockIdx.x * 256 + threadIdx.x;   // exactly N*64/4 threads
    int fb = (q & 15);                         // float4 index within feature row
    const float4* S4 = reinterpret_cast<const float4*>(SUM);
    float4 s1 = S4[fb];            // sums for features fb*4..fb*4+3
    float4 s2 = S4[16 + fb];       // sq-sums
    float4 gm = reinterpret_cast<const float4*>(gamma)[fb];
    float4 bt = reinterpret_cast<const float4*>(beta)[fb];
    const float inv_n = 1.f / N_ATOMS;
    float4 x = reinterpret_cast<const float4*>(X)[q];
    float4 o;
    {
        float mean = s1.x * inv_n, msq = s2.x * inv_n;
        float sc = rsqrtf(msq - mean * mean + 1e-5f) * gm.x;
        o.x = softplus_f(x.x * sc + (bt.x - mean * sc));
    }
    {
        float mean = s1.y * inv_n, msq = s2.y * inv_n;
        float sc = rsqrtf(msq - mean * mean + 1e-5f) * gm.y;
        o.y = softplus_f(x.y * sc + (bt.y - mean * sc));
    }
    {
        float mean = s1.z * inv_n, msq = s2.z * inv_n;
        float sc = rsqrtf(msq - mean * mean + 1e-5f) * gm.z;
        o.z = softplus_f(x.z * sc + (bt.z - mean * sc));
    }
    {
        float mean = s1.w * inv_n, msq = s2.w * inv_n;
        float sc = rsqrtf(msq - mean * mean + 1e-5f) * gm.w;
        o.w = softplus_f(x.w * sc + (bt.w - mean * sc));
    }
    reinterpret_cast<float4*>(X)[q] = o;
}

extern "C" void kernel_launch(void* const* d_in, const int* in_sizes, int n_in,
                              void* d_out, int out_size, void* d_ws, size_t ws_size,
                              hipStream_t stream)
{
    const float* atom  = (const float*)d_in[0];
    const float* nbr   = (const float*)d_in[1];
    const float* W     = (const float*)d_in[2];
    const float* bias  = (const float*)d_in[3];
    const float* gamma = (const float*)d_in[4];
    const float* beta  = (const float*)d_in[5];
    const int*   idx   = (const int*)d_in[6];
    float* X = (float*)d_out;   // x pre-BN lives in d_out, finalized in place

    char* ws = (char*)d_ws;
    unsigned* abf = (unsigned*)ws;                                     // N*32 u32 (12.8 MB)
    float* SUM    = (float*)(ws + (size_t)N_ATOMS * 32 * 4);           // 128 f32

    const int blocks = (N_GROUPS + 3) / 4;   // 1563: one group per wave
    hipLaunchKernelGGL(k_prep,  dim3(blocks), dim3(256), 0, stream, atom, abf, SUM);
    hipLaunchKernelGGL(k_msg,   dim3(blocks), dim3(256), 0, stream,
                       atom, nbr, W, bias, idx, abf, X, SUM);
    hipLaunchKernelGGL(k_final, dim3(6250),   dim3(256), 0, stream, X, SUM, gamma, beta);
}